// Round 4
// baseline (1200.939 us; speedup 1.0000x reference)
//
#include <hip/hip_runtime.h>
#include <cstdint>
#include <cstddef>

typedef unsigned short u16;
typedef __attribute__((ext_vector_type(8))) short short8;
typedef __attribute__((ext_vector_type(4))) float f32x4;

#define T_SEQ 8192
#define NH 16
#define HD 128
#define NCH 64
#define KDIM 2048

constexpr float EPS = 1e-5f;
constexpr float SCALE = 0.08838834764831845f;   // 128^-0.5

__device__ __forceinline__ u16 f2bf(float f) {
  union { float f; unsigned u; } v; v.f = f;
  unsigned r = v.u + 0x7fffu + ((v.u >> 16) & 1u);
  return (u16)(r >> 16);
}
__device__ __forceinline__ float bf2f(u16 h) {
  union { unsigned u; float f; } v; v.u = ((unsigned)h) << 16;
  return v.f;
}
__device__ __forceinline__ f32x4 mfma16(short8 a, short8 b, f32x4 c) {
  return __builtin_amdgcn_mfma_f32_16x16x32_bf16(a, b, c, 0, 0, 0);
}
// async global->LDS, 16B per lane; lds dest is wave-uniform base + lane*16B
__device__ __forceinline__ void gl2lds(const u16* g, u16* l) {
  __builtin_amdgcn_global_load_lds(
      (const __attribute__((address_space(1))) void*)g,
      (__attribute__((address_space(3))) void*)l, 16, 0, 0);
}

// ---------------- fp32 -> bf16 cast ----------------
__global__ __launch_bounds__(256) void cast_f32_bf16(const float* __restrict__ src,
                                                     u16* __restrict__ dst, long n) {
  long i = ((long)blockIdx.x * 256 + threadIdx.x) * 8;
  if (i >= n) return;
  float4 a = *(const float4*)(src + i);
  float4 b = *(const float4*)(src + i + 4);
  alignas(16) u16 u[8] = {f2bf(a.x), f2bf(a.y), f2bf(a.z), f2bf(a.w),
                          f2bf(b.x), f2bf(b.y), f2bf(b.z), f2bf(b.w)};
  *(int4*)(dst + i) = *(const int4*)u;
}

// ---------------- weight transpose+cast: W [K][N] fp32 -> Wt [N][K] bf16 ----
__global__ __launch_bounds__(256) void transpose_cast(const float* __restrict__ W,
                                                      u16* __restrict__ Wt, int K, int N) {
  __shared__ u16 tile[64][72];
  int n0 = blockIdx.x * 64, k0 = blockIdx.y * 64;
  int tx = threadIdx.x, ty = threadIdx.y; // (64,4)
  for (int r = ty; r < 64; r += 4)
    tile[r][tx] = f2bf(W[(size_t)(k0 + r) * N + n0 + tx]);
  __syncthreads();
  for (int r = ty; r < 64; r += 4)
    Wt[(size_t)(n0 + r) * K + k0 + tx] = tile[tx][r];
}

// ---------------- main GEMM: C = epi(A @ Bt^T) ----------------
// A [8192][2048] bf16, Bt [N][2048] bf16. 128x128 tile, BK=32, 4 waves 2x2.
// global_load_lds width=16 staging, unpadded LDS [128][32].
// EPI 0: fp32 out (final Wo gemm).
// EPI 2: fused QKV+gate epilogue, N=8192:
//   part=bn>>4: 0=q,1=k (silu+rmsnorm+rope, in-LDS), 2=v (silu scatter),
//   3=gate (raw fp32 into gate_f)
template <int EPI>
__global__ __launch_bounds__(256) void gemm_k(const u16* __restrict__ A,
                                              const u16* __restrict__ Bt, int N,
                                              float* __restrict__ Cf,
                                              u16* __restrict__ q_t,
                                              u16* __restrict__ k_t,
                                              u16* __restrict__ v_t,
                                              float* __restrict__ gate_f,
                                              const int* __restrict__ positions,
                                              const float* __restrict__ q_ln_w,
                                              const float* __restrict__ k_ln_w) {
  __shared__ u16 lA[128 * 32];
  __shared__ u16 lB[128 * 32];
  const int tid = threadIdx.x;
  const int bm = blockIdx.y, bn = blockIdx.x;
  const int wave = tid >> 6, lane = tid & 63;
  const int wm = (wave >> 1) * 64, wn = (wave & 1) * 64;
  const int lr = lane & 15, lg = lane >> 4;
  const int srow = wave * 32 + (lane >> 2);
  const int scol = (lane & 3) * 8;
  const u16* gA = A + ((size_t)bm * 128 + srow) * KDIM + scol;
  const u16* gB = Bt + ((size_t)bn * 128 + srow) * KDIM + scol;
  u16* lA0 = &lA[wave * 1024];
  u16* lB0 = &lB[wave * 1024];

  f32x4 acc[4][4];
  #pragma unroll
  for (int i = 0; i < 4; i++)
    #pragma unroll
    for (int j = 0; j < 4; j++) acc[i][j] = (f32x4){0.f, 0.f, 0.f, 0.f};

  for (int k0 = 0; k0 < KDIM; k0 += 32) {
    __syncthreads();
    gl2lds(gA + k0, lA0);
    gl2lds(gA + (size_t)16 * KDIM + k0, lA0 + 512);
    gl2lds(gB + k0, lB0);
    gl2lds(gB + (size_t)16 * KDIM + k0, lB0 + 512);
    __syncthreads();
    short8 af[4], bfr[4];
    #pragma unroll
    for (int i = 0; i < 4; i++)
      af[i] = *(const short8*)&lA[(wm + i * 16 + lr) * 32 + lg * 8];
    #pragma unroll
    for (int j = 0; j < 4; j++)
      bfr[j] = *(const short8*)&lB[(wn + j * 16 + lr) * 32 + lg * 8];
    #pragma unroll
    for (int i = 0; i < 4; i++)
      #pragma unroll
      for (int j = 0; j < 4; j++)
        acc[i][j] = mfma16(af[i], bfr[j], acc[i][j]);
  }

  if (EPI == 0) {
    #pragma unroll
    for (int i = 0; i < 4; i++)
      #pragma unroll
      for (int j = 0; j < 4; j++)
        #pragma unroll
        for (int r = 0; r < 4; r++) {
          int row = bm * 128 + wm + i * 16 + lg * 4 + r;
          int col = bn * 128 + wn + j * 16 + lr;
          Cf[(size_t)row * N + col] = acc[i][j][r];
        }
    return;
  }

  // ---- EPI == 2: fused QKV+gate ----
  const int part = bn >> 4;      // uniform per block
  const int h = bn & 15;

  if (part == 3) {               // gate: raw fp32
    #pragma unroll
    for (int i = 0; i < 4; i++)
      #pragma unroll
      for (int j = 0; j < 4; j++)
        #pragma unroll
        for (int r = 0; r < 4; r++) {
          int row = bm * 128 + wm + i * 16 + lg * 4 + r;
          int col = (bn * 128 + wn + j * 16 + lr) & 2047;
          gate_f[(size_t)row * 2048 + col] = acc[i][j][r];
        }
    return;
  }
  if (part == 2) {               // v: silu scatter
    #pragma unroll
    for (int i = 0; i < 4; i++)
      #pragma unroll
      for (int j = 0; j < 4; j++)
        #pragma unroll
        for (int r = 0; r < 4; r++) {
          int row = bm * 128 + wm + i * 16 + lg * 4 + r;
          int d = (wn + j * 16 + lr) & 127;
          float v = acc[i][j][r];
          float s = v / (1.0f + __expf(-v));
          v_t[((size_t)h * T_SEQ + row) * HD + d] = f2bf(s);
        }
    return;
  }

  // part 0/1: q or k. silu -> LDS tile -> rmsnorm -> rope -> store
  __shared__ u16 tile[128 * 136];
  __shared__ float psum[128][2];
  #pragma unroll
  for (int i = 0; i < 4; i++)
    #pragma unroll
    for (int j = 0; j < 4; j++)
      #pragma unroll
      for (int r = 0; r < 4; r++) {
        int row = wm + i * 16 + lg * 4 + r;
        int d = wn + j * 16 + lr;
        float v = acc[i][j][r];
        float s = v / (1.0f + __expf(-v));
        tile[row * 136 + d] = f2bf(s);
      }
  __syncthreads();
  const int row = tid & 127, half = tid >> 7;
  {
    float ss = 0.f;
    #pragma unroll
    for (int j = 0; j < 8; j++) {
      short8 v8 = *(const short8*)&tile[row * 136 + half * 64 + j * 8];
      #pragma unroll
      for (int m = 0; m < 8; m++) {
        float v = bf2f((u16)v8[m]);
        ss += v * v;
      }
    }
    psum[row][half] = ss;
  }
  __syncthreads();
  {
    float rms = rsqrtf((psum[row][0] + psum[row][1]) * (1.0f / 128.0f) + EPS);
    const float* w = (part == 0) ? q_ln_w : k_ln_w;
    const float sc = (part == 0) ? SCALE : 1.0f;
    const int trow = bm * 128 + row;
    const float pos = (float)positions[trow];
    u16* dst = ((part == 0) ? q_t : k_t) + ((size_t)h * T_SEQ + trow) * HD + half * 64;
    #pragma unroll
    for (int j = 0; j < 8; j++) {
      short8 a8 = *(const short8*)&tile[row * 136 + half * 64 + j * 8];
      short8 b8 = *(const short8*)&tile[row * 136 + (half ^ 1) * 64 + j * 8];
      alignas(16) u16 outv[8];
      #pragma unroll
      for (int m = 0; m < 8; m++) {
        int d = half * 64 + j * 8 + m;
        int i2 = d & 63;
        float invf = exp2f((float)i2 * (-19.194593f / 64.0f));
        float ang = pos * invf;
        float cv = cosf(ang), sv = sinf(ang);
        float x = bf2f((u16)a8[m]) * rms * w[d];
        float y = bf2f((u16)b8[m]) * rms * w[d ^ 64];
        float o = (half == 0) ? (x * cv - y * sv) : (x * cv + y * sv);
        outv[m] = f2bf(o * sc);
      }
      *(int4*)(dst + j * 8) = *(const int4*)outv;
    }
  }
}

// ---------------- phase B: G[h][c][e][d] = sum_{t in chunk} V[t][e] K[t][d] ----
__global__ __launch_bounds__(256) void attn_phaseB(const u16* __restrict__ k_t,
                                                   const u16* __restrict__ v_t,
                                                   u16* __restrict__ G) {
  const int c = blockIdx.x, h = blockIdx.y;
  __shared__ u16 lV[128 * 72];
  __shared__ u16 lK[128 * 72];
  const int tid = threadIdx.x, wave = tid >> 6, lane = tid & 63;
  const int wm = (wave >> 1) * 64, wn = (wave & 1) * 64;
  const int lr = lane & 15, lg = lane >> 4;
  f32x4 acc[4][4];
  #pragma unroll
  for (int i = 0; i < 4; i++)
    #pragma unroll
    for (int j = 0; j < 4; j++) acc[i][j] = (f32x4){0.f, 0.f, 0.f, 0.f};

  const int tr = tid >> 2, seg = (tid & 3) * 32;
  for (int h2 = 0; h2 < 2; h2++) {
    __syncthreads();
    const u16* vsrc = v_t + ((size_t)h * T_SEQ + c * 128 + h2 * 64 + tr) * HD + seg;
    const u16* ksrc = k_t + ((size_t)h * T_SEQ + c * 128 + h2 * 64 + tr) * HD + seg;
    #pragma unroll
    for (int m = 0; m < 32; m += 8) {
      int4 rv = *(const int4*)(vsrc + m);
      int4 rk = *(const int4*)(ksrc + m);
      const u16* ev = (const u16*)&rv;
      const u16* ek = (const u16*)&rk;
      #pragma unroll
      for (int j = 0; j < 8; j++) {
        lV[(seg + m + j) * 72 + tr] = ev[j];
        lK[(seg + m + j) * 72 + tr] = ek[j];
      }
    }
    __syncthreads();
    #pragma unroll
    for (int kk = 0; kk < 64; kk += 32) {
      short8 af[4], bfr[4];
      #pragma unroll
      for (int i = 0; i < 4; i++)
        af[i] = *(const short8*)&lV[(wm + i * 16 + lr) * 72 + kk + lg * 8];
      #pragma unroll
      for (int j = 0; j < 4; j++)
        bfr[j] = *(const short8*)&lK[(wn + j * 16 + lr) * 72 + kk + lg * 8];
      #pragma unroll
      for (int i = 0; i < 4; i++)
        #pragma unroll
        for (int j = 0; j < 4; j++)
          acc[i][j] = mfma16(af[i], bfr[j], acc[i][j]);
    }
  }
  u16* Gp = G + ((size_t)h * NCH + c) * 16384;
  #pragma unroll
  for (int i = 0; i < 4; i++)
    #pragma unroll
    for (int j = 0; j < 4; j++)
      #pragma unroll
      for (int r = 0; r < 4; r++)
        Gp[(wm + i * 16 + lg * 4 + r) * 128 + wn + j * 16 + lr] = f2bf(acc[i][j][r]);
}

// exclusive prefix over chunk axis, bf16 storage / fp32 accumulator, in place
__global__ __launch_bounds__(256) void prefix_S(u16* __restrict__ G) {
  long idx = (long)blockIdx.x * 256 + threadIdx.x;   // over 16*16384
  int h = (int)(idx >> 14);
  int ed = (int)(idx & 16383);
  float run = 0.f;
  size_t base = (size_t)h * NCH * 16384 + ed;
  for (int c = 0; c < NCH; c++) {
    float g = bf2f(G[base + (size_t)c * 16384]);
    G[base + (size_t)c * 16384] = f2bf(run);
    run += g;
  }
}

// ---------------- phase C: O = tril(Q K^T) V + Q S ----------------
__global__ __launch_bounds__(256) void attn_phaseC(const u16* __restrict__ q_t,
                                                   const u16* __restrict__ k_t,
                                                   const u16* __restrict__ v_t,
                                                   const u16* __restrict__ G,
                                                   u16* __restrict__ o_bf) {
  const int c = blockIdx.x, h = blockIdx.y;
  __shared__ u16 lP[128 * 136];
  __shared__ u16 lV[128 * 72];
  const int tid = threadIdx.x, wave = tid >> 6, lane = tid & 63;
  const int wm = wave * 32;
  const int lr = lane & 15, lg = lane >> 4;

  f32x4 acc1[2][8], acc2[2][8];
  #pragma unroll
  for (int i = 0; i < 2; i++)
    #pragma unroll
    for (int j = 0; j < 8; j++) {
      acc1[i][j] = (f32x4){0.f, 0.f, 0.f, 0.f};
      acc2[i][j] = (f32x4){0.f, 0.f, 0.f, 0.f};
    }

  const u16* Sp = G + ((size_t)h * NCH + c) * 16384;
  const u16* qbase = q_t + ((size_t)h * T_SEQ + c * 128) * HD;
  const u16* kbase = k_t + ((size_t)h * T_SEQ + c * 128) * HD;

  #pragma unroll
  for (int kk = 0; kk < 128; kk += 32) {
    short8 af[2];
    #pragma unroll
    for (int i = 0; i < 2; i++)
      af[i] = *(const short8*)(qbase + (wm + i * 16 + lr) * HD + kk + lg * 8);
    #pragma unroll
    for (int j = 0; j < 8; j++) {
      short8 bK = *(const short8*)(kbase + (j * 16 + lr) * HD + kk + lg * 8);
      short8 bS = *(const short8*)(Sp + (j * 16 + lr) * 128 + kk + lg * 8);
      #pragma unroll
      for (int i = 0; i < 2; i++) {
        acc1[i][j] = mfma16(af[i], bK, acc1[i][j]);
        acc2[i][j] = mfma16(af[i], bS, acc2[i][j]);
      }
    }
  }
  #pragma unroll
  for (int i = 0; i < 2; i++)
    #pragma unroll
    for (int j = 0; j < 8; j++)
      #pragma unroll
      for (int r = 0; r < 4; r++) {
        int row = wm + i * 16 + lg * 4 + r;
        int col = j * 16 + lr;
        float v = (col <= row) ? acc1[i][j][r] : 0.0f;
        lP[row * 136 + col] = f2bf(v);
      }

  const int tr = tid >> 2, seg = (tid & 3) * 32;
  for (int sh2 = 0; sh2 < 2; sh2++) {
    __syncthreads();
    const u16* vsrc = v_t + ((size_t)h * T_SEQ + c * 128 + sh2 * 64 + tr) * HD + seg;
    #pragma unroll
    for (int m = 0; m < 32; m += 8) {
      int4 rv = *(const int4*)(vsrc + m);
      const u16* ev = (const u16*)&rv;
      #pragma unroll
      for (int j = 0; j < 8; j++) lV[(seg + m + j) * 72 + tr] = ev[j];
    }
    __syncthreads();
    #pragma unroll
    for (int kk = 0; kk < 64; kk += 32) {
      short8 af[2];
      #pragma unroll
      for (int i = 0; i < 2; i++)
        af[i] = *(const short8*)&lP[(wm + i * 16 + lr) * 136 + sh2 * 64 + kk + lg * 8];
      #pragma unroll
      for (int j = 0; j < 8; j++) {
        short8 bV = *(const short8*)&lV[(j * 16 + lr) * 72 + kk + lg * 8];
        #pragma unroll
        for (int i = 0; i < 2; i++)
          acc2[i][j] = mfma16(af[i], bV, acc2[i][j]);
      }
    }
  }
  #pragma unroll
  for (int i = 0; i < 2; i++)
    #pragma unroll
    for (int j = 0; j < 8; j++)
      #pragma unroll
      for (int r = 0; r < 4; r++) {
        int row = wm + i * 16 + lg * 4 + r;
        int e = j * 16 + lr;
        o_bf[(size_t)(c * 128 + row) * 2048 + h * 128 + e] = f2bf(acc2[i][j][r]);
      }
}

// ---------------- gated rmsnorm: gated = sigmoid(gate) * rmsnorm(o) ----------------
__global__ __launch_bounds__(256) void gated_kernel(const u16* __restrict__ o_bf,
                                                    const float* __restrict__ gate_f,
                                                    const float* __restrict__ g_norm_w,
                                                    u16* __restrict__ gated_bf) {
  const int t = blockIdx.x, tid = threadIdx.x;
  const u16* orow = o_bf + (size_t)t * 2048;
  float vals[8], ss = 0.f;
  #pragma unroll
  for (int j = 0; j < 8; j++) {
    float v = bf2f(orow[tid + j * 256]);
    vals[j] = v;
    ss += v * v;
  }
  #pragma unroll
  for (int off = 32; off > 0; off >>= 1) ss += __shfl_xor(ss, off);
  __shared__ float sh[4];
  if ((tid & 63) == 0) sh[tid >> 6] = ss;
  __syncthreads();
  ss = sh[0] + sh[1] + sh[2] + sh[3];
  float r = rsqrtf(ss * (1.0f / 2048.0f) + EPS);
  const float* grow = gate_f + (size_t)t * 2048;
  u16* drow = gated_bf + (size_t)t * 2048;
  #pragma unroll
  for (int j = 0; j < 8; j++) {
    int col = tid + j * 256;
    float normed = vals[j] * r * g_norm_w[col];
    float g = grow[col];
    float sg = 1.0f / (1.0f + __expf(-g));
    drow[col] = f2bf(normed * sg);
  }
}

// ---------------- launch ----------------
extern "C" void kernel_launch(void* const* d_in, const int* in_sizes, int n_in,
                              void* d_out, int out_size, void* d_ws, size_t ws_size,
                              hipStream_t stream) {
  const float* x = (const float*)d_in[0];
  const int* positions = (const int*)d_in[1];
  const float* Wqkv = (const float*)d_in[2];
  const float* q_ln_w = (const float*)d_in[3];
  const float* k_ln_w = (const float*)d_in[4];
  const float* Wg = (const float*)d_in[5];
  const float* g_norm_w = (const float*)d_in[6];
  const float* Wo = (const float*)d_in[7];
  float* out = (float*)d_out;

  // Regions (32 MiB each), aliased by lifetime:
  //  R0: WcT ([Wqkv|Wg]^T) -> G -> gated
  //  R1: x_bf -> o_bf
  //  R2: q_t -> WoT (8M)
  //  R3: k_t
  //  R4: v_t
  //  gate (fp32) lives in d_out until final GEMM overwrites it.
  char* ws = (char*)d_ws;
  const size_t M32 = (size_t)32 * 1024 * 1024;
  u16* WcT   = (u16*)ws;
  u16* G     = (u16*)ws;
  u16* gated = (u16*)ws;
  u16* x_bf  = (u16*)(ws + M32);
  u16* o_bf  = x_bf;
  u16* q_t   = (u16*)(ws + 2 * M32);
  u16* WoT   = q_t;
  u16* k_t   = (u16*)(ws + 3 * M32);
  u16* v_t   = (u16*)(ws + 4 * M32);
  float* gate_f = out;
  const size_t needed = 5 * M32;   // 167,772,160
  if (ws_size < needed) return;

  cast_f32_bf16<<<8192, 256, 0, stream>>>(x, x_bf, (long)8192 * 2048);
  transpose_cast<<<dim3(96, 32), dim3(64, 4), 0, stream>>>(Wqkv, WcT, 2048, 6144);
  transpose_cast<<<dim3(32, 32), dim3(64, 4), 0, stream>>>(Wg, WcT + (size_t)6144 * 2048, 2048, 2048);

  gemm_k<2><<<dim3(64, 64), 256, 0, stream>>>(x_bf, WcT, 8192, nullptr,
                                              q_t, k_t, v_t, gate_f,
                                              positions, q_ln_w, k_ln_w);

  attn_phaseB<<<dim3(64, 16), 256, 0, stream>>>(k_t, v_t, G);
  prefix_S<<<1024, 256, 0, stream>>>(G);
  attn_phaseC<<<dim3(64, 16), 256, 0, stream>>>(q_t, k_t, v_t, G, o_bf);

  gated_kernel<<<8192, 256, 0, stream>>>(o_bf, gate_f, g_norm_w, gated);

  transpose_cast<<<dim3(32, 32), dim3(64, 4), 0, stream>>>(Wo, WoT, 2048, 2048);
  gemm_k<0><<<dim3(16, 64), 256, 0, stream>>>(gated, WoT, 2048, out,
                                              nullptr, nullptr, nullptr, nullptr,
                                              nullptr, nullptr, nullptr);
}